// Round 8
// baseline (216.758 us; speedup 1.0000x reference)
//
#include <hip/hip_runtime.h>
#include <hip/hip_cooperative_groups.h>
#include <cstdint>

namespace cg = cooperative_groups;

#define K_V_C   1.05f
#define G_DIFF  4.0e-4f   // G_MAX - G_MIN
#define KPAD    3456      // k = 3*j + level, j padded to 1152 (= 32*108)

typedef __attribute__((ext_vector_type(8))) short short8;
typedef __attribute__((ext_vector_type(4))) float f32x4;

// I_REF rows 1..3 (row 0 is all zeros)
__device__ __constant__ float c_I1[9] = {-0.00015f,-0.00011f,-7e-05f,-3e-05f,0.f,3e-05f,7e-05f,0.00011f,0.00015f};
__device__ __constant__ float c_I2[9] = {-0.0005f,-0.00035f,-0.00022f,-9e-05f,0.f,9e-05f,0.00022f,0.00035f,0.0005f};
__device__ __constant__ float c_I3[9] = {-0.0009f,-0.0006f,-0.00037f,-0.00015f,0.f,0.00015f,0.00037f,0.0006f,0.0009f};

__device__ inline unsigned short f2bf(float f) {   // fp32 -> bf16 RNE
  unsigned int u = __float_as_uint(f);
  u += 0x7FFFu + ((u >> 16) & 1u);
  return (unsigned short)(u >> 16);
}

__device__ inline void interp3(float v, float& u1, float& u2, float& u3) {
  const float sf = v * 3.3333333333333335f + 4.0f;   // (v+1.2)/0.3
  float fs = floorf(sf);
  fs = fminf(fmaxf(fs, 0.f), 7.f);
  const int   s  = (int)fs;
  const float fr = fminf(fmaxf(sf - fs, 0.f), 1.f);
  u1 = fmaf(fr, c_I1[s+1] - c_I1[s], c_I1[s]);
  u2 = fmaf(fr, c_I2[s+1] - c_I2[s], c_I2[s]);
  u3 = fmaf(fr, c_I3[s+1] - c_I3[s], c_I3[s]);
}

__device__ inline void coeff3(float g, float& c1, float& c2, float& c3) {
  const float ga  = fabsf(g);
  const float sgn = (g > 0.f) ? 1.f : ((g < 0.f) ? -1.f : 0.f);
  const int   idx = (ga >= 3e-4f) ? 2 : ((ga >= 1e-4f) ? 1 : 0);
  const float g0   = (idx == 0) ? 0.f : ((idx == 1) ? 1e-4f : 3e-4f);
  const float invd = (idx == 0) ? 1e4f : 5e3f;
  const float t    = (ga - g0) * invd;
  const float clo = sgn * (1.f - t), chi = sgn * t;
  c1 = (idx == 0) ? chi : ((idx == 1) ? clo : 0.f);
  c2 = (idx == 1) ? chi : ((idx == 2) ? clo : 0.f);
  c3 = (idx == 2) ? chi : 0.f;
}

__device__ inline float max8(float4 a, float4 b) {
  return fmaxf(fmaxf(fmaxf(fabsf(a.x), fabsf(a.y)), fmaxf(fabsf(a.z), fabsf(a.w))),
               fmaxf(fmaxf(fabsf(b.x), fabsf(b.y)), fmaxf(fabsf(b.z), fabsf(b.w))));
}

// ---------------------------------------------------------------------------
// MEGA kernel (cooperative): phase1 maxabs -> phase2 prep U/C -> phase3 GEMM.
//   512 blocks x 256 threads (2 blocks/CU), 16.6 KB LDS.
// ---------------------------------------------------------------------------
__global__ __launch_bounds__(256) void mega_kernel(
    const float* __restrict__ x, const float* __restrict__ w,
    const float* __restrict__ bias, float* __restrict__ partials,
    unsigned short* __restrict__ Ub, unsigned short* __restrict__ Cb,
    float* __restrict__ out) {
  cg::grid_group grid = cg::this_grid();
  __shared__ __align__(16) float sh[4160];   // wt[16][260] / P[4][256]
  const int t = threadIdx.x, bid = blockIdx.x;
  const int lane = t & 63, wv = t >> 6;

  // ---------- phase 1: block-partial max(|w|,|b|) ----------
  {
    const int i0 = bid * 512 + t;                 // f4 index into w (262144)
    float m = max8(((const float4*)w)[i0], ((const float4*)w)[i0 + 256]);
    if (bid == 0) {
      const float4 bv = ((const float4*)bias)[t]; // 256 f4 of bias
      m = fmaxf(m, max8(bv, bv));
    }
    #pragma unroll
    for (int o = 32; o > 0; o >>= 1) m = fmaxf(m, __shfl_down(m, o, 64));
    if (lane == 0) sh[wv] = m;
    __syncthreads();
    if (t == 0)
      partials[bid] = fmaxf(fmaxf(sh[0], sh[1]), fmaxf(sh[2], sh[3]));
  }
  __threadfence();
  grid.sync();

  // ---------- all blocks: reduce 512 partials to maxw ----------
  float maxw;
  {
    const float4 p1 = ((const float4*)partials)[lane];
    const float4 p2 = ((const float4*)partials)[lane + 64];
    float m = fmaxf(fmaxf(fmaxf(p1.x, p1.y), fmaxf(p1.z, p1.w)),
                    fmaxf(fmaxf(p2.x, p2.y), fmaxf(p2.z, p2.w)));
    #pragma unroll
    for (int o = 1; o < 64; o <<= 1) m = fmaxf(m, __shfl_xor(m, o, 64));
    maxw = m;
  }

  // ---------- phase 2: prep U (blocks 0..143) / C^T (blocks 144..431) ----------
  if (bid < 144) {
    const int idx = bid * 256 + t;       // 36864 = 128 b x 288 j4-groups
    const int b = idx / 288, j4 = idx - b * 288;
    unsigned short h[12];
    if (j4 < 256) {
      const float4 xv = *(const float4*)(x + b * 1024 + j4 * 4);
      const float vx[4] = {xv.x, xv.y, xv.z, xv.w};
      #pragma unroll
      for (int jj = 0; jj < 4; ++jj) {
        float u1, u2, u3;
        interp3(K_V_C * vx[jj], u1, u2, u3);
        h[jj*3] = f2bf(u1); h[jj*3+1] = f2bf(u2); h[jj*3+2] = f2bf(u3);
      }
    } else {
      #pragma unroll
      for (int i = 0; i < 12; ++i) h[i] = 0;
      if (j4 == 256) {                   // j = 1024: the ones/bias column
        float u1, u2, u3;
        interp3(K_V_C, u1, u2, u3);
        h[0] = f2bf(u1); h[1] = f2bf(u2); h[2] = f2bf(u3);
      }
    }
    ushort4* dst = (ushort4*)(Ub + (size_t)b * KPAD + j4 * 12);
    dst[0] = make_ushort4(h[0], h[1], h[2],  h[3]);
    dst[1] = make_ushort4(h[4], h[5], h[6],  h[7]);
    dst[2] = make_ushort4(h[8], h[9], h[10], h[11]);
  } else if (bid < 432) {
    const int cid = bid - 144;                       // 288 = 4 m-tiles x 72 j-tiles
    const int m0 = (cid & 3) * 256, j0 = (cid >> 2) * 16;
    #pragma unroll
    for (int s = 0; s < 4; ++s) {                    // stage w[16 j][256 m] tile
      const int r = s * 4 + (t >> 6);
      const int c = (t & 63) * 4;
      const int j = j0 + r;
      float4 v = make_float4(0.f, 0.f, 0.f, 0.f);
      if (j < 1024)       v = *(const float4*)(w + j * 1024 + m0 + c);
      else if (j == 1024) v = *(const float4*)(bias + m0 + c);
      *(float4*)&sh[r * 260 + c] = v;
    }
    __syncthreads();
    const float kG = G_DIFF / maxw;
    const int m = m0 + t;
    unsigned short* dst = Cb + (size_t)m * KPAD + j0 * 3;
    #pragma unroll
    for (int g = 0; g < 4; ++g) {
      unsigned short h[12];
      #pragma unroll
      for (int jj = 0; jj < 4; ++jj) {
        float c1, c2, c3;
        coeff3(kG * sh[(g * 4 + jj) * 260 + t], c1, c2, c3);
        h[jj*3] = f2bf(c1); h[jj*3+1] = f2bf(c2); h[jj*3+2] = f2bf(c3);
      }
      ushort4* d4 = (ushort4*)(dst + g * 12);
      d4[0] = make_ushort4(h[0], h[1], h[2],  h[3]);
      d4[1] = make_ushort4(h[4], h[5], h[6],  h[7]);
      d4[2] = make_ushort4(h[8], h[9], h[10], h[11]);
    }
  }
  __threadfence();
  grid.sync();

  // ---------- phase 3: GEMM, split-K x4, fused scale ----------
  {
    const int la = lane & 15, kg = lane >> 4;
    const int b0 = (bid >> 6) * 16;
    const int n0 = (bid & 63) * 16;
    const size_t kbase = (size_t)wv * 864 + kg * 8;
    const unsigned short* Ap = Ub + (size_t)(b0 + la) * KPAD + kbase;
    const unsigned short* Bp = Cb + (size_t)(n0 + la) * KPAD + kbase;

    f32x4 acc = {0.f, 0.f, 0.f, 0.f};
    #pragma unroll
    for (int g = 0; g < 3; ++g) {        // 27 steps = 3 groups of 9 in flight
      short8 a[9], b[9];
      #pragma unroll
      for (int i = 0; i < 9; ++i) {
        a[i] = *(const short8*)(Ap + (g * 9 + i) * 32);
        b[i] = *(const short8*)(Bp + (g * 9 + i) * 32);
      }
      #pragma unroll
      for (int i = 0; i < 9; ++i)
        acc = __builtin_amdgcn_mfma_f32_16x16x32_bf16(a[i], b[i], acc, 0, 0, 0);
    }

    *(float4*)&sh[wv * 256 + lane * 4] = make_float4(acc[0], acc[1], acc[2], acc[3]);
    const float scale = maxw * (1.0f / (K_V_C * G_DIFF));
    __syncthreads();

    const int l2 = t & 63, ai = t >> 6;
    const float s = sh[0*256 + l2*4 + ai] + sh[1*256 + l2*4 + ai] +
                    sh[2*256 + l2*4 + ai] + sh[3*256 + l2*4 + ai];
    const int row = b0 + (l2 >> 4) * 4 + ai;   // D: col = lane&15, row = kg*4+r
    const int col = n0 + (l2 & 15);
    out[(size_t)row * 1024 + col] = s * scale;
  }
}

// ---------------------------------------------------------------------------
// Fallback A (coop launch unavailable): round-7 3-dispatch path.
// ---------------------------------------------------------------------------
__device__ inline float partials_max1024(const float* __restrict__ partials, int t) {
  const float4 pv = ((const float4*)partials)[t & 63];
  float m = fmaxf(fmaxf(pv.x, pv.y), fmaxf(pv.z, pv.w));
  #pragma unroll
  for (int o = 1; o < 64; o <<= 1) m = fmaxf(m, __shfl_xor(m, o, 64));
  return m;
}

__global__ __launch_bounds__(256) void maxabs_kernel(const float* __restrict__ w,
                                                     const float* __restrict__ b,
                                                     float* __restrict__ partials) {
  const int i = blockIdx.x * 256 + threadIdx.x;
  float4 v = ((const float4*)w)[i];
  float m = fmaxf(fmaxf(fabsf(v.x), fabsf(v.y)), fmaxf(fabsf(v.z), fabsf(v.w)));
  if (i < 256) {
    float4 bv = ((const float4*)b)[i];
    m = fmaxf(m, fmaxf(fmaxf(fabsf(bv.x), fabsf(bv.y)),
                       fmaxf(fabsf(bv.z), fabsf(bv.w))));
  }
  #pragma unroll
  for (int o = 32; o > 0; o >>= 1) m = fmaxf(m, __shfl_down(m, o, 64));
  __shared__ float red[4];
  if ((threadIdx.x & 63) == 0) red[threadIdx.x >> 6] = m;
  __syncthreads();
  if (threadIdx.x == 0)
    partials[blockIdx.x] = fmaxf(fmaxf(red[0], red[1]), fmaxf(red[2], red[3]));
}

__global__ __launch_bounds__(256) void prep_kernel(
    const float* __restrict__ x, const float* __restrict__ w,
    const float* __restrict__ bias, const float* __restrict__ partials,
    unsigned short* __restrict__ Ub, unsigned short* __restrict__ Cb) {
  __shared__ float wt[32][260];
  const int bid = blockIdx.x, t = threadIdx.x;
  if (bid < 144) {
    const int idx = bid * 256 + t;
    const int b = idx / 288, j4 = idx - b * 288;
    unsigned short h[12];
    if (j4 < 256) {
      const float4 xv = *(const float4*)(x + b * 1024 + j4 * 4);
      const float vx[4] = {xv.x, xv.y, xv.z, xv.w};
      #pragma unroll
      for (int jj = 0; jj < 4; ++jj) {
        float u1, u2, u3;
        interp3(K_V_C * vx[jj], u1, u2, u3);
        h[jj*3] = f2bf(u1); h[jj*3+1] = f2bf(u2); h[jj*3+2] = f2bf(u3);
      }
    } else {
      #pragma unroll
      for (int i = 0; i < 12; ++i) h[i] = 0;
      if (j4 == 256) {
        float u1, u2, u3;
        interp3(K_V_C, u1, u2, u3);
        h[0] = f2bf(u1); h[1] = f2bf(u2); h[2] = f2bf(u3);
      }
    }
    ushort4* dst = (ushort4*)(Ub + (size_t)b * KPAD + j4 * 12);
    dst[0] = make_ushort4(h[0], h[1], h[2],  h[3]);
    dst[1] = make_ushort4(h[4], h[5], h[6],  h[7]);
    dst[2] = make_ushort4(h[8], h[9], h[10], h[11]);
  } else {
    const int cid = bid - 144;
    const int m0 = (cid & 3) * 256, j0 = (cid >> 2) * 32;
    #pragma unroll
    for (int s = 0; s < 8; ++s) {
      const int r = s * 4 + (t >> 6);
      const int c = (t & 63) * 4;
      const int j = j0 + r;
      float4 v = make_float4(0.f, 0.f, 0.f, 0.f);
      if (j < 1024)       v = *(const float4*)(w + j * 1024 + m0 + c);
      else if (j == 1024) v = *(const float4*)(bias + m0 + c);
      *(float4*)&wt[r][c] = v;
    }
    const float kG = G_DIFF / partials_max1024(partials, t);
    __syncthreads();
    const int m = m0 + t;
    unsigned short* dst = Cb + (size_t)m * KPAD + j0 * 3;
    #pragma unroll
    for (int g = 0; g < 8; ++g) {
      unsigned short h[12];
      #pragma unroll
      for (int jj = 0; jj < 4; ++jj) {
        float c1, c2, c3;
        coeff3(kG * wt[g * 4 + jj][t], c1, c2, c3);
        h[jj*3] = f2bf(c1); h[jj*3+1] = f2bf(c2); h[jj*3+2] = f2bf(c3);
      }
      ushort4* d4 = (ushort4*)(dst + g * 12);
      d4[0] = make_ushort4(h[0], h[1], h[2],  h[3]);
      d4[1] = make_ushort4(h[4], h[5], h[6],  h[7]);
      d4[2] = make_ushort4(h[8], h[9], h[10], h[11]);
    }
  }
}

__global__ __launch_bounds__(256, 2) void gemm_kernel(
    const unsigned short* __restrict__ Ub, const unsigned short* __restrict__ Cb,
    const float* __restrict__ partials, float* __restrict__ out) {
  __shared__ float P[4][256];
  const int t = threadIdx.x;
  const int wv = t >> 6;
  const int lane = t & 63, la = lane & 15, kg = lane >> 4;
  const int b0 = (blockIdx.x >> 6) * 16;
  const int n0 = (blockIdx.x & 63) * 16;
  const size_t kbase = (size_t)wv * 864 + kg * 8;
  const unsigned short* Ap = Ub + (size_t)(b0 + la) * KPAD + kbase;
  const unsigned short* Bp = Cb + (size_t)(n0 + la) * KPAD + kbase;
  f32x4 acc = {0.f, 0.f, 0.f, 0.f};
  #pragma unroll
  for (int g = 0; g < 3; ++g) {
    short8 a[9], b[9];
    #pragma unroll
    for (int i = 0; i < 9; ++i) {
      a[i] = *(const short8*)(Ap + (g * 9 + i) * 32);
      b[i] = *(const short8*)(Bp + (g * 9 + i) * 32);
    }
    #pragma unroll
    for (int i = 0; i < 9; ++i)
      acc = __builtin_amdgcn_mfma_f32_16x16x32_bf16(a[i], b[i], acc, 0, 0, 0);
  }
  *(float4*)&P[wv][lane * 4] = make_float4(acc[0], acc[1], acc[2], acc[3]);
  const float scale = partials_max1024(partials, t) * (1.0f / (K_V_C * G_DIFF));
  __syncthreads();
  const int l2 = t & 63, ai = t >> 6;
  const float s = P[0][l2*4+ai] + P[1][l2*4+ai] + P[2][l2*4+ai] + P[3][l2*4+ai];
  const int row = b0 + (l2 >> 4) * 4 + ai;
  const int col = n0 + (l2 & 15);
  out[(size_t)row * 1024 + col] = s * scale;
}

// ---------------------------------------------------------------------------
// Fallback B (tiny ws): atomic-based, needs only 4 bytes of ws.
// ---------------------------------------------------------------------------
__global__ __launch_bounds__(256) void maxabs_atomic_kernel(
    const float* __restrict__ w, const float* __restrict__ b,
    unsigned int* __restrict__ wsmax) {
  const int NW4 = 262144, NB4 = 256;
  float m = 0.f;
  for (int i = blockIdx.x * blockDim.x + threadIdx.x; i < NW4 + NB4;
       i += gridDim.x * blockDim.x) {
    float4 v = (i < NW4) ? ((const float4*)w)[i] : ((const float4*)b)[i - NW4];
    m = fmaxf(m, fmaxf(fmaxf(fabsf(v.x), fabsf(v.y)),
                       fmaxf(fabsf(v.z), fabsf(v.w))));
  }
  #pragma unroll
  for (int o = 32; o > 0; o >>= 1) m = fmaxf(m, __shfl_down(m, o, 64));
  __shared__ float red[4];
  if ((threadIdx.x & 63) == 0) red[threadIdx.x >> 6] = m;
  __syncthreads();
  if (threadIdx.x == 0)
    atomicMax(wsmax, __float_as_uint(fmaxf(fmaxf(red[0], red[1]),
                                           fmaxf(red[2], red[3]))));
}

__global__ __launch_bounds__(256) void memristor_atomic_kernel(
    const float* __restrict__ x, const float* __restrict__ w,
    const float* __restrict__ bias, const unsigned int* __restrict__ wsmax,
    float* __restrict__ out) {
  __shared__ float4 U[2048];
  const int tid = threadIdx.x;
  const float maxw  = __uint_as_float(*wsmax);
  const float kG    = G_DIFF / maxw;
  const float scale = maxw * (1.0f / (K_V_C * G_DIFF));
  const int mq = tid & 15, bg = tid >> 4;
  const int m0 = blockIdx.x * 64 + mq * 4;
  const int swz = bg & 7;
  float acc[4][8];
  #pragma unroll
  for (int a = 0; a < 4; ++a)
    #pragma unroll
    for (int c = 0; c < 8; ++c) acc[a][c] = 0.f;
  for (int sc = blockIdx.y; sc < 65; sc += 16) {
    const int j0 = sc * 16;
    const int nj = min(16, 1025 - j0);
    __syncthreads();
    #pragma unroll
    for (int k = 0; k < 8; ++k) {
      const int e = k * 256 + tid;
      const int jl = e & 15, b = e >> 4;
      const int jg = j0 + jl;
      if (jg <= 1024) {
        const float v = (jg < 1024) ? K_V_C * x[b * 1024 + jg] : K_V_C;
        float u1, u2, u3;
        interp3(v, u1, u2, u3);
        U[b * 16 + (jl ^ ((b >> 3) & 7))] = make_float4(0.f, u1, u2, u3);
      }
    }
    __syncthreads();
    for (int jl = 0; jl < nj; ++jl) {
      const int jg = j0 + jl;
      const float4 wv = (jg < 1024) ? *(const float4*)(w + jg * 1024 + m0)
                                    : *(const float4*)(bias + m0);
      const float warr[4] = {wv.x, wv.y, wv.z, wv.w};
      float c1[4], c2[4], c3[4];
      #pragma unroll
      for (int mi = 0; mi < 4; ++mi) coeff3(kG * warr[mi], c1[mi], c2[mi], c3[mi]);
      const int base = bg * 128 + (jl ^ swz);
      #pragma unroll
      for (int bb = 0; bb < 8; ++bb) {
        const float4 u = U[base + bb * 16];
        #pragma unroll
        for (int mi = 0; mi < 4; ++mi)
          acc[mi][bb] = fmaf(c1[mi], u.y, fmaf(c2[mi], u.z, fmaf(c3[mi], u.w, acc[mi][bb])));
      }
    }
  }
  #pragma unroll
  for (int bb = 0; bb < 8; ++bb) {
    const int b = bg * 8 + bb;
    #pragma unroll
    for (int mi = 0; mi < 4; ++mi)
      atomicAdd(&out[b * 1024 + m0 + mi], acc[mi][bb] * scale);
  }
}

// ---------------------------------------------------------------------------
extern "C" void kernel_launch(void* const* d_in, const int* in_sizes, int n_in,
                              void* d_out, int out_size, void* d_ws, size_t ws_size,
                              hipStream_t stream) {
  const float* x = (const float*)d_in[0];   // (128, 1024)
  const float* w = (const float*)d_in[1];   // (1024, 1024)
  const float* b = (const float*)d_in[2];   // (1024,)
  float* out = (float*)d_out;               // (128, 1024) fp32

  float*          partials = (float*)((char*)d_ws + 128);               // <=1024 f32
  unsigned short* Ub = (unsigned short*)((char*)d_ws + 8192);           // 884,736 B
  unsigned short* Cb = (unsigned short*)((char*)d_ws + (1u << 20));     // 7,077,888 B
  const size_t need = (1u << 20) + (size_t)1024 * KPAD * 2;             // ~8.1 MB

  if (ws_size >= need) {
    void* args[] = {(void*)&x, (void*)&w, (void*)&b, (void*)&partials,
                    (void*)&Ub, (void*)&Cb, (void*)&out};
    hipError_t err = hipLaunchCooperativeKernel((const void*)mega_kernel,
                                                dim3(512), dim3(256),
                                                args, 0, stream);
    if (err != hipSuccess) {              // fallback A: 3-dispatch path
      maxabs_kernel<<<1024, 256, 0, stream>>>(w, b, partials);
      prep_kernel<<<288, 256, 0, stream>>>(x, w, b, partials, Ub, Cb);
      gemm_kernel<<<512, 256, 0, stream>>>(Ub, Cb, partials, out);
    }
  } else {                                // fallback B: tiny ws, atomic path
    unsigned int* wsmax = (unsigned int*)d_ws;
    hipMemsetAsync(wsmax, 0, 4, stream);
    maxabs_atomic_kernel<<<256, 256, 0, stream>>>(w, b, wsmax);
    hipMemsetAsync(out, 0, (size_t)out_size * sizeof(float), stream);
    dim3 grid(16, 16);
    memristor_atomic_kernel<<<grid, 256, 0, stream>>>(x, w, b, wsmax, out);
  }
}

// Round 9
// 29.420 us; speedup vs baseline: 7.3677x; 7.3677x over previous
//
#include <hip/hip_runtime.h>
#include <cstdint>

#define K_V_C   1.05f
#define G_DIFF  4.0e-4f   // G_MAX - G_MIN
#define KP4     4608      // k = 4*j + level (level 3 = zero pad), j padded to 1152

typedef __attribute__((ext_vector_type(8))) short short8;
typedef __attribute__((ext_vector_type(4))) float f32x4;

// I_REF rows 1..3 (row 0 is all zeros)
__device__ __constant__ float c_I1[9] = {-0.00015f,-0.00011f,-7e-05f,-3e-05f,0.f,3e-05f,7e-05f,0.00011f,0.00015f};
__device__ __constant__ float c_I2[9] = {-0.0005f,-0.00035f,-0.00022f,-9e-05f,0.f,9e-05f,0.00022f,0.00035f,0.0005f};
__device__ __constant__ float c_I3[9] = {-0.0009f,-0.0006f,-0.00037f,-0.00015f,0.f,0.00015f,0.00037f,0.0006f,0.0009f};

__device__ inline unsigned short f2bf(float f) {   // fp32 -> bf16 RNE
  unsigned int u = __float_as_uint(f);
  u += 0x7FFFu + ((u >> 16) & 1u);
  return (unsigned short)(u >> 16);
}

__device__ inline void interp3(float v, float& u1, float& u2, float& u3) {
  const float sf = v * 3.3333333333333335f + 4.0f;   // (v+1.2)/0.3
  float fs = floorf(sf);
  fs = fminf(fmaxf(fs, 0.f), 7.f);
  const int   s  = (int)fs;
  const float fr = fminf(fmaxf(sf - fs, 0.f), 1.f);
  u1 = fmaf(fr, c_I1[s+1] - c_I1[s], c_I1[s]);
  u2 = fmaf(fr, c_I2[s+1] - c_I2[s], c_I2[s]);
  u3 = fmaf(fr, c_I3[s+1] - c_I3[s], c_I3[s]);
}

__device__ inline void coeff3(float g, float& c1, float& c2, float& c3) {
  const float ga  = fabsf(g);
  const float sgn = (g > 0.f) ? 1.f : ((g < 0.f) ? -1.f : 0.f);
  const int   idx = (ga >= 3e-4f) ? 2 : ((ga >= 1e-4f) ? 1 : 0);
  const float g0   = (idx == 0) ? 0.f : ((idx == 1) ? 1e-4f : 3e-4f);
  const float invd = (idx == 0) ? 1e4f : 5e3f;
  const float t    = (ga - g0) * invd;
  const float clo = sgn * (1.f - t), chi = sgn * t;
  c1 = (idx == 0) ? chi : ((idx == 1) ? clo : 0.f);
  c2 = (idx == 1) ? chi : ((idx == 2) ? clo : 0.f);
  c3 = (idx == 2) ? chi : 0.f;
}

// ---------------------------------------------------------------------------
// Dispatch 1: blocks 0..1023  -> per-block max(|w|,|b|) partials (no atomics)
//             blocks 1024..1167 -> prep U bf16 [128][KP4], k = 4*j + level
// ---------------------------------------------------------------------------
__global__ __launch_bounds__(256) void prep1_kernel(
    const float* __restrict__ x, const float* __restrict__ w,
    const float* __restrict__ bias, float* __restrict__ partials,
    unsigned short* __restrict__ Ub) {
  const int t = threadIdx.x, bid = blockIdx.x;
  if (bid < 1024) {                       // ---- maxabs partial ----
    const int i = bid * 256 + t;          // one float4 of w per thread
    const float4 v = ((const float4*)w)[i];
    float m = fmaxf(fmaxf(fabsf(v.x), fabsf(v.y)), fmaxf(fabsf(v.z), fabsf(v.w)));
    if (i < 256) {
      const float4 bv = ((const float4*)bias)[i];
      m = fmaxf(m, fmaxf(fmaxf(fabsf(bv.x), fabsf(bv.y)),
                         fmaxf(fabsf(bv.z), fabsf(bv.w))));
    }
    #pragma unroll
    for (int o = 32; o > 0; o >>= 1) m = fmaxf(m, __shfl_down(m, o, 64));
    __shared__ float red[4];
    if ((t & 63) == 0) red[t >> 6] = m;
    __syncthreads();
    if (t == 0)
      partials[bid] = fmaxf(fmaxf(red[0], red[1]), fmaxf(red[2], red[3]));
  } else {                                // ---- prep U ----
    const int idx = (bid - 1024) * 256 + t;   // 36864 = 128 b x 288 j4-groups
    const int b = idx / 288, j4 = idx - b * 288;
    ushort4 o0 = make_ushort4(0,0,0,0), o1 = o0, o2 = o0, o3 = o0;
    if (j4 < 256) {
      const float4 xv = ((const float4*)x)[b * 256 + j4];
      float u1, u2, u3;
      interp3(K_V_C * xv.x, u1, u2, u3); o0 = make_ushort4(f2bf(u1), f2bf(u2), f2bf(u3), 0);
      interp3(K_V_C * xv.y, u1, u2, u3); o1 = make_ushort4(f2bf(u1), f2bf(u2), f2bf(u3), 0);
      interp3(K_V_C * xv.z, u1, u2, u3); o2 = make_ushort4(f2bf(u1), f2bf(u2), f2bf(u3), 0);
      interp3(K_V_C * xv.w, u1, u2, u3); o3 = make_ushort4(f2bf(u1), f2bf(u2), f2bf(u3), 0);
    } else if (j4 == 256) {               // j = 1024: ones/bias column
      float u1, u2, u3;
      interp3(K_V_C, u1, u2, u3);
      o0 = make_ushort4(f2bf(u1), f2bf(u2), f2bf(u3), 0);
    }
    ushort4* dst = (ushort4*)(Ub + (size_t)b * KP4 + j4 * 16);
    dst[0] = o0; dst[1] = o1; dst[2] = o2; dst[3] = o3;
  }
}

// ---------------------------------------------------------------------------
// Dispatch 2: GEMM y = scale * U . C^T, C-fragments built IN REGISTERS.
//   512 blocks (one 16x16 tile) x 4 waves (split-K x4, 1152 k = 288 j each).
//   Per MFMA step: lane loads w[j0][m], w[j0+1][m], computes coeffs, packs
//   the bf16 B-fragment {c1,c2,c3,0, c1',c2',c3',0}. LDS cross-wave reduce.
// ---------------------------------------------------------------------------
__global__ __launch_bounds__(256, 2) void fusedgemm_kernel(
    const float* __restrict__ w, const float* __restrict__ bias,
    const float* __restrict__ partials, const unsigned short* __restrict__ Ub,
    float* __restrict__ out) {
  __shared__ float P[4][256];
  const int t = threadIdx.x;
  const int wv = t >> 6, lane = t & 63, la = lane & 15, kg = lane >> 4;
  const int b0 = (blockIdx.x >> 6) * 16;
  const int n0 = (blockIdx.x & 63) * 16;
  const int m  = n0 + la;

  // full maxw from all 1024 partials (fixes round-7's 1/4-sample bug)
  float mx = 0.f;
  #pragma unroll
  for (int i = 0; i < 4; ++i) {
    const float4 p = ((const float4*)partials)[lane + i * 64];
    mx = fmaxf(mx, fmaxf(fmaxf(p.x, p.y), fmaxf(p.z, p.w)));
  }
  #pragma unroll
  for (int o = 1; o < 64; o <<= 1) mx = fmaxf(mx, __shfl_xor(mx, o, 64));
  const float maxw = mx;
  const float kG   = G_DIFF / maxw;

  const unsigned short* Ap = Ub + (size_t)(b0 + la) * KP4 + wv * 1152 + kg * 8;
  const int jb = wv * 288 + kg * 2;      // j of frag slot 0 at step ks: jb + ks*8
  f32x4 acc = {0.f, 0.f, 0.f, 0.f};
  const int nks = (wv == 3) ? 21 : 36;   // wave 3: j > 1024 beyond step 20

  #pragma unroll 6
  for (int ks = 0; ks < nks; ++ks) {
    const short8 a = *(const short8*)(Ap + ks * 32);
    const int j0 = jb + ks * 8;          // this lane's two j's: j0, j0+1
    float wa = 0.f, wb = 0.f;
    if (j0 < 1024)       wa = w[j0 * 1024 + m];
    else if (j0 == 1024) wa = bias[m];
    if (j0 < 1023)       wb = w[j0 * 1024 + 1024 + m];
    else if (j0 == 1023) wb = bias[m];
    float a1, a2, a3, b1, b2, b3;
    coeff3(kG * wa, a1, a2, a3);
    coeff3(kG * wb, b1, b2, b3);
    short8 bf;
    bf[0] = (short)f2bf(a1); bf[1] = (short)f2bf(a2);
    bf[2] = (short)f2bf(a3); bf[3] = 0;
    bf[4] = (short)f2bf(b1); bf[5] = (short)f2bf(b2);
    bf[6] = (short)f2bf(b3); bf[7] = 0;
    acc = __builtin_amdgcn_mfma_f32_16x16x32_bf16(a, bf, acc, 0, 0, 0);
  }

  *(float4*)&P[wv][lane * 4] = make_float4(acc[0], acc[1], acc[2], acc[3]);
  __syncthreads();
  const float scale = maxw * (1.0f / (K_V_C * G_DIFF));
  const int l2 = t & 63, ai = t >> 6;
  const float s = P[0][l2*4 + ai] + P[1][l2*4 + ai] +
                  P[2][l2*4 + ai] + P[3][l2*4 + ai];
  const int row = b0 + (l2 >> 4) * 4 + ai;   // D: col = lane&15, row = kg*4+r
  const int col = n0 + (l2 & 15);
  out[(size_t)row * 1024 + col] = s * scale;
}

// ---------------------------------------------------------------------------
// Fallback (tiny ws): atomic-based path, needs only 4 bytes of ws.
// ---------------------------------------------------------------------------
__global__ __launch_bounds__(256) void maxabs_atomic_kernel(
    const float* __restrict__ w, const float* __restrict__ b,
    unsigned int* __restrict__ wsmax) {
  const int NW4 = 262144, NB4 = 256;
  float m = 0.f;
  for (int i = blockIdx.x * blockDim.x + threadIdx.x; i < NW4 + NB4;
       i += gridDim.x * blockDim.x) {
    float4 v = (i < NW4) ? ((const float4*)w)[i] : ((const float4*)b)[i - NW4];
    m = fmaxf(m, fmaxf(fmaxf(fabsf(v.x), fabsf(v.y)),
                       fmaxf(fabsf(v.z), fabsf(v.w))));
  }
  #pragma unroll
  for (int o = 32; o > 0; o >>= 1) m = fmaxf(m, __shfl_down(m, o, 64));
  __shared__ float red[4];
  if ((threadIdx.x & 63) == 0) red[threadIdx.x >> 6] = m;
  __syncthreads();
  if (threadIdx.x == 0)
    atomicMax(wsmax, __float_as_uint(fmaxf(fmaxf(red[0], red[1]),
                                           fmaxf(red[2], red[3]))));
}

__global__ __launch_bounds__(256) void memristor_atomic_kernel(
    const float* __restrict__ x, const float* __restrict__ w,
    const float* __restrict__ bias, const unsigned int* __restrict__ wsmax,
    float* __restrict__ out) {
  __shared__ float4 U[2048];
  const int tid = threadIdx.x;
  const float maxw  = __uint_as_float(*wsmax);
  const float kG    = G_DIFF / maxw;
  const float scale = maxw * (1.0f / (K_V_C * G_DIFF));
  const int mq = tid & 15, bg = tid >> 4;
  const int m0 = blockIdx.x * 64 + mq * 4;
  const int swz = bg & 7;
  float acc[4][8];
  #pragma unroll
  for (int a = 0; a < 4; ++a)
    #pragma unroll
    for (int c = 0; c < 8; ++c) acc[a][c] = 0.f;
  for (int sc = blockIdx.y; sc < 65; sc += 16) {
    const int j0 = sc * 16;
    const int nj = min(16, 1025 - j0);
    __syncthreads();
    #pragma unroll
    for (int k = 0; k < 8; ++k) {
      const int e = k * 256 + tid;
      const int jl = e & 15, b = e >> 4;
      const int jg = j0 + jl;
      if (jg <= 1024) {
        const float v = (jg < 1024) ? K_V_C * x[b * 1024 + jg] : K_V_C;
        float u1, u2, u3;
        interp3(v, u1, u2, u3);
        U[b * 16 + (jl ^ ((b >> 3) & 7))] = make_float4(0.f, u1, u2, u3);
      }
    }
    __syncthreads();
    for (int jl = 0; jl < nj; ++jl) {
      const int jg = j0 + jl;
      const float4 wv = (jg < 1024) ? *(const float4*)(w + jg * 1024 + m0)
                                    : *(const float4*)(bias + m0);
      const float warr[4] = {wv.x, wv.y, wv.z, wv.w};
      float c1[4], c2[4], c3[4];
      #pragma unroll
      for (int mi = 0; mi < 4; ++mi) coeff3(kG * warr[mi], c1[mi], c2[mi], c3[mi]);
      const int base = bg * 128 + (jl ^ swz);
      #pragma unroll
      for (int bb = 0; bb < 8; ++bb) {
        const float4 u = U[base + bb * 16];
        #pragma unroll
        for (int mi = 0; mi < 4; ++mi)
          acc[mi][bb] = fmaf(c1[mi], u.y, fmaf(c2[mi], u.z, fmaf(c3[mi], u.w, acc[mi][bb])));
      }
    }
  }
  #pragma unroll
  for (int bb = 0; bb < 8; ++bb) {
    const int b = bg * 8 + bb;
    #pragma unroll
    for (int mi = 0; mi < 4; ++mi)
      atomicAdd(&out[b * 1024 + m0 + mi], acc[mi][bb] * scale);
  }
}

// ---------------------------------------------------------------------------
extern "C" void kernel_launch(void* const* d_in, const int* in_sizes, int n_in,
                              void* d_out, int out_size, void* d_ws, size_t ws_size,
                              hipStream_t stream) {
  const float* x = (const float*)d_in[0];   // (128, 1024)
  const float* w = (const float*)d_in[1];   // (1024, 1024)
  const float* b = (const float*)d_in[2];   // (1024,)
  float* out = (float*)d_out;               // (128, 1024) fp32

  float*          partials = (float*)((char*)d_ws + 128);        // 1024 f32
  unsigned short* Ub = (unsigned short*)((char*)d_ws + 8192);    // 1,179,648 B
  const size_t need = 8192 + (size_t)128 * KP4 * 2;              // ~1.13 MB

  if (ws_size >= need) {
    prep1_kernel<<<1168, 256, 0, stream>>>(x, w, b, partials, Ub);
    fusedgemm_kernel<<<512, 256, 0, stream>>>(w, b, partials, Ub, out);
  } else {                                 // fallback: tiny ws, atomic path
    unsigned int* wsmax = (unsigned int*)d_ws;
    hipMemsetAsync(wsmax, 0, 4, stream);
    maxabs_atomic_kernel<<<256, 256, 0, stream>>>(w, b, wsmax);
    hipMemsetAsync(out, 0, (size_t)out_size * sizeof(float), stream);
    dim3 grid(16, 16);
    memristor_atomic_kernel<<<grid, 256, 0, stream>>>(x, w, b, wsmax, out);
  }
}

// Round 10
// 25.506 us; speedup vs baseline: 8.4982x; 1.1534x over previous
//
#include <hip/hip_runtime.h>
#include <cstdint>

#define K_V_C   1.05f
#define G_DIFF  4.0e-4f   // G_MAX - G_MIN
#define KP4     4608      // k = 4*j + level (level 3 = zero pad), j padded to 1152

typedef __attribute__((ext_vector_type(8))) short short8;
typedef __attribute__((ext_vector_type(4))) float f32x4;

// I_REF rows 1..3 (row 0 is all zeros)
__device__ __constant__ float c_I1[9] = {-0.00015f,-0.00011f,-7e-05f,-3e-05f,0.f,3e-05f,7e-05f,0.00011f,0.00015f};
__device__ __constant__ float c_I2[9] = {-0.0005f,-0.00035f,-0.00022f,-9e-05f,0.f,9e-05f,0.00022f,0.00035f,0.0005f};
__device__ __constant__ float c_I3[9] = {-0.0009f,-0.0006f,-0.00037f,-0.00015f,0.f,0.00015f,0.00037f,0.0006f,0.0009f};

__device__ inline unsigned short f2bf(float f) {   // fp32 -> bf16 RNE
  unsigned int u = __float_as_uint(f);
  u += 0x7FFFu + ((u >> 16) & 1u);
  return (unsigned short)(u >> 16);
}

__device__ inline void interp3(float v, float& u1, float& u2, float& u3) {
  const float sf = v * 3.3333333333333335f + 4.0f;   // (v+1.2)/0.3
  float fs = floorf(sf);
  fs = fminf(fmaxf(fs, 0.f), 7.f);
  const int   s  = (int)fs;
  const float fr = fminf(fmaxf(sf - fs, 0.f), 1.f);
  u1 = fmaf(fr, c_I1[s+1] - c_I1[s], c_I1[s]);
  u2 = fmaf(fr, c_I2[s+1] - c_I2[s], c_I2[s]);
  u3 = fmaf(fr, c_I3[s+1] - c_I3[s], c_I3[s]);
}

__device__ inline void coeff3(float g, float& c1, float& c2, float& c3) {
  const float ga  = fabsf(g);
  const float sgn = (g > 0.f) ? 1.f : ((g < 0.f) ? -1.f : 0.f);
  const int   idx = (ga >= 3e-4f) ? 2 : ((ga >= 1e-4f) ? 1 : 0);
  const float g0   = (idx == 0) ? 0.f : ((idx == 1) ? 1e-4f : 3e-4f);
  const float invd = (idx == 0) ? 1e4f : 5e3f;
  const float t    = (ga - g0) * invd;
  const float clo = sgn * (1.f - t), chi = sgn * t;
  c1 = (idx == 0) ? chi : ((idx == 1) ? clo : 0.f);
  c2 = (idx == 1) ? chi : ((idx == 2) ? clo : 0.f);
  c3 = (idx == 2) ? chi : 0.f;
}

// ---------------------------------------------------------------------------
// Dispatch 1: blocks 0..1023  -> per-block max(|w|,|b|) partials (no atomics)
//             blocks 1024..1167 -> prep U bf16 [128][KP4], k = 4*j + level
// ---------------------------------------------------------------------------
__global__ __launch_bounds__(256) void prep1_kernel(
    const float* __restrict__ x, const float* __restrict__ w,
    const float* __restrict__ bias, float* __restrict__ partials,
    unsigned short* __restrict__ Ub) {
  const int t = threadIdx.x, bid = blockIdx.x;
  if (bid < 1024) {                       // ---- maxabs partial ----
    const int i = bid * 256 + t;          // one float4 of w per thread
    const float4 v = ((const float4*)w)[i];
    float m = fmaxf(fmaxf(fabsf(v.x), fabsf(v.y)), fmaxf(fabsf(v.z), fabsf(v.w)));
    if (i < 256) {
      const float4 bv = ((const float4*)bias)[i];
      m = fmaxf(m, fmaxf(fmaxf(fabsf(bv.x), fabsf(bv.y)),
                         fmaxf(fabsf(bv.z), fabsf(bv.w))));
    }
    #pragma unroll
    for (int o = 32; o > 0; o >>= 1) m = fmaxf(m, __shfl_down(m, o, 64));
    __shared__ float red[4];
    if ((t & 63) == 0) red[t >> 6] = m;
    __syncthreads();
    if (t == 0)
      partials[bid] = fmaxf(fmaxf(red[0], red[1]), fmaxf(red[2], red[3]));
  } else {                                // ---- prep U ----
    const int idx = (bid - 1024) * 256 + t;   // 36864 = 128 b x 288 j4-groups
    const int b = idx / 288, j4 = idx - b * 288;
    ushort4 o0 = make_ushort4(0,0,0,0), o1 = o0, o2 = o0, o3 = o0;
    if (j4 < 256) {
      const float4 xv = ((const float4*)x)[b * 256 + j4];
      float u1, u2, u3;
      interp3(K_V_C * xv.x, u1, u2, u3); o0 = make_ushort4(f2bf(u1), f2bf(u2), f2bf(u3), 0);
      interp3(K_V_C * xv.y, u1, u2, u3); o1 = make_ushort4(f2bf(u1), f2bf(u2), f2bf(u3), 0);
      interp3(K_V_C * xv.z, u1, u2, u3); o2 = make_ushort4(f2bf(u1), f2bf(u2), f2bf(u3), 0);
      interp3(K_V_C * xv.w, u1, u2, u3); o3 = make_ushort4(f2bf(u1), f2bf(u2), f2bf(u3), 0);
    } else if (j4 == 256) {               // j = 1024: ones/bias column
      float u1, u2, u3;
      interp3(K_V_C, u1, u2, u3);
      o0 = make_ushort4(f2bf(u1), f2bf(u2), f2bf(u3), 0);
    }
    ushort4* dst = (ushort4*)(Ub + (size_t)b * KP4 + j4 * 16);
    dst[0] = o0; dst[1] = o1; dst[2] = o2; dst[3] = o3;
  }
}

// ---------------------------------------------------------------------------
// Dispatch 2: GEMM y = scale * U . C^T, C-fragments built from an LDS-staged
//   w-panel. 512 blocks (one 16x16 tile) x 8 waves (split-K x8, 144 j each).
//   LDS: w-panel transposed [16 m][1024 j] f32 (64 KB); inner-loop w-read is
//   a 16-lane same-address broadcast (conflict-free). P[8][256] aliases the
//   panel after a barrier. Branch-free 18-step inner loop.
// ---------------------------------------------------------------------------
__global__ __launch_bounds__(512, 4) void fusedgemm_kernel(
    const float* __restrict__ w, const float* __restrict__ bias,
    const float* __restrict__ partials, const unsigned short* __restrict__ Ub,
    float* __restrict__ out) {
  __shared__ __align__(16) float lds[16384];   // 64 KB exactly
  const int t = threadIdx.x;
  const int wv = t >> 6, lane = t & 63, la = lane & 15, kg = lane >> 4;
  const int b0 = (blockIdx.x >> 6) * 16;
  const int n0 = (blockIdx.x & 63) * 16;
  const int m  = n0 + la;

  // ---- stage w-panel transposed: lds[mm][j] = w[j][n0+mm] ----
  #pragma unroll
  for (int i = 0; i < 8; ++i) {
    const int idx = i * 512 + t;               // 4096 float4 of the panel
    const int row = idx >> 2, c4 = idx & 3;    // row = j, c4*4.. = m-sub
    const float4 v = *(const float4*)(w + (size_t)row * 1024 + n0 + c4 * 4);
    lds[(c4 * 4 + 0) * 1024 + row] = v.x;
    lds[(c4 * 4 + 1) * 1024 + row] = v.y;
    lds[(c4 * 4 + 2) * 1024 + row] = v.z;
    lds[(c4 * 4 + 3) * 1024 + row] = v.w;
  }

  // ---- maxw from all 1024 partials ----
  float mx = 0.f;
  #pragma unroll
  for (int i = 0; i < 4; ++i) {
    const float4 p = ((const float4*)partials)[lane + i * 64];
    mx = fmaxf(mx, fmaxf(fmaxf(p.x, p.y), fmaxf(p.z, p.w)));
  }
  #pragma unroll
  for (int o = 1; o < 64; o <<= 1) mx = fmaxf(mx, __shfl_xor(mx, o, 64));
  const float maxw = mx;
  const float kG   = G_DIFF / maxw;
  const float bv   = bias[m];
  __syncthreads();

  // ---- 18-step branch-free MFMA loop (wave = k-slice of 576 = 144 j) ----
  const unsigned short* Ap = Ub + (size_t)(b0 + la) * KP4 + wv * 576 + kg * 8;
  const int jb = wv * 144 + kg * 2;
  const float* wrow = &lds[la * 1024];
  f32x4 acc = {0.f, 0.f, 0.f, 0.f};
  #pragma unroll 6
  for (int ks = 0; ks < 18; ++ks) {
    const short8 a = *(const short8*)(Ap + ks * 32);
    const int j0 = jb + ks * 8;                // this lane's two j's: j0, j0+1
    const float ra = wrow[min(j0, 1023)];
    const float rb = wrow[min(j0 + 1, 1023)];
    const float wa = (j0 < 1024) ? ra : ((j0 == 1024) ? bv : 0.f);
    const float wb = (j0 + 1 < 1024) ? rb : ((j0 + 1 == 1024) ? bv : 0.f);
    float a1, a2, a3, b1, b2, b3;
    coeff3(kG * wa, a1, a2, a3);
    coeff3(kG * wb, b1, b2, b3);
    short8 bf;
    bf[0] = (short)f2bf(a1); bf[1] = (short)f2bf(a2);
    bf[2] = (short)f2bf(a3); bf[3] = 0;
    bf[4] = (short)f2bf(b1); bf[5] = (short)f2bf(b2);
    bf[6] = (short)f2bf(b3); bf[7] = 0;
    acc = __builtin_amdgcn_mfma_f32_16x16x32_bf16(a, bf, acc, 0, 0, 0);
  }

  // ---- cross-wave K-reduce (P aliases the w-panel) + fused scale ----
  __syncthreads();                             // all waves done reading panel
  *(float4*)&lds[wv * 256 + lane * 4] = make_float4(acc[0], acc[1], acc[2], acc[3]);
  __syncthreads();
  if (t < 256) {
    float s = 0.f;
    #pragma unroll
    for (int ww = 0; ww < 8; ++ww) s += lds[ww * 256 + t];
    const int l2 = t >> 2, ai = t & 3;         // D: col = lane&15, row = kg*4+r
    const int row = b0 + ((l2 >> 4) << 2) + ai;
    const int col = n0 + (l2 & 15);
    out[(size_t)row * 1024 + col] = s * (maxw * (1.0f / (K_V_C * G_DIFF)));
  }
}

// ---------------------------------------------------------------------------
// Fallback (tiny ws): atomic-based path, needs only 4 bytes of ws.
// ---------------------------------------------------------------------------
__global__ __launch_bounds__(256) void maxabs_atomic_kernel(
    const float* __restrict__ w, const float* __restrict__ b,
    unsigned int* __restrict__ wsmax) {
  const int NW4 = 262144, NB4 = 256;
  float m = 0.f;
  for (int i = blockIdx.x * blockDim.x + threadIdx.x; i < NW4 + NB4;
       i += gridDim.x * blockDim.x) {
    float4 v = (i < NW4) ? ((const float4*)w)[i] : ((const float4*)b)[i - NW4];
    m = fmaxf(m, fmaxf(fmaxf(fabsf(v.x), fabsf(v.y)),
                       fmaxf(fabsf(v.z), fabsf(v.w))));
  }
  #pragma unroll
  for (int o = 32; o > 0; o >>= 1) m = fmaxf(m, __shfl_down(m, o, 64));
  __shared__ float red[4];
  if ((threadIdx.x & 63) == 0) red[threadIdx.x >> 6] = m;
  __syncthreads();
  if (threadIdx.x == 0)
    atomicMax(wsmax, __float_as_uint(fmaxf(fmaxf(red[0], red[1]),
                                           fmaxf(red[2], red[3]))));
}

__global__ __launch_bounds__(256) void memristor_atomic_kernel(
    const float* __restrict__ x, const float* __restrict__ w,
    const float* __restrict__ bias, const unsigned int* __restrict__ wsmax,
    float* __restrict__ out) {
  __shared__ float4 U[2048];
  const int tid = threadIdx.x;
  const float maxw  = __uint_as_float(*wsmax);
  const float kG    = G_DIFF / maxw;
  const float scale = maxw * (1.0f / (K_V_C * G_DIFF));
  const int mq = tid & 15, bg = tid >> 4;
  const int m0 = blockIdx.x * 64 + mq * 4;
  const int swz = bg & 7;
  float acc[4][8];
  #pragma unroll
  for (int a = 0; a < 4; ++a)
    #pragma unroll
    for (int c = 0; c < 8; ++c) acc[a][c] = 0.f;
  for (int sc = blockIdx.y; sc < 65; sc += 16) {
    const int j0 = sc * 16;
    const int nj = min(16, 1025 - j0);
    __syncthreads();
    #pragma unroll
    for (int k = 0; k < 8; ++k) {
      const int e = k * 256 + tid;
      const int jl = e & 15, b = e >> 4;
      const int jg = j0 + jl;
      if (jg <= 1024) {
        const float v = (jg < 1024) ? K_V_C * x[b * 1024 + jg] : K_V_C;
        float u1, u2, u3;
        interp3(v, u1, u2, u3);
        U[b * 16 + (jl ^ ((b >> 3) & 7))] = make_float4(0.f, u1, u2, u3);
      }
    }
    __syncthreads();
    for (int jl = 0; jl < nj; ++jl) {
      const int jg = j0 + jl;
      const float4 wv = (jg < 1024) ? *(const float4*)(w + jg * 1024 + m0)
                                    : *(const float4*)(bias + m0);
      const float warr[4] = {wv.x, wv.y, wv.z, wv.w};
      float c1[4], c2[4], c3[4];
      #pragma unroll
      for (int mi = 0; mi < 4; ++mi) coeff3(kG * warr[mi], c1[mi], c2[mi], c3[mi]);
      const int base = bg * 128 + (jl ^ swz);
      #pragma unroll
      for (int bb = 0; bb < 8; ++bb) {
        const float4 u = U[base + bb * 16];
        #pragma unroll
        for (int mi = 0; mi < 4; ++mi)
          acc[mi][bb] = fmaf(c1[mi], u.y, fmaf(c2[mi], u.z, fmaf(c3[mi], u.w, acc[mi][bb])));
      }
    }
  }
  #pragma unroll
  for (int bb = 0; bb < 8; ++bb) {
    const int b = bg * 8 + bb;
    #pragma unroll
    for (int mi = 0; mi < 4; ++mi)
      atomicAdd(&out[b * 1024 + m0 + mi], acc[mi][bb] * scale);
  }
}

// ---------------------------------------------------------------------------
extern "C" void kernel_launch(void* const* d_in, const int* in_sizes, int n_in,
                              void* d_out, int out_size, void* d_ws, size_t ws_size,
                              hipStream_t stream) {
  const float* x = (const float*)d_in[0];   // (128, 1024)
  const float* w = (const float*)d_in[1];   // (1024, 1024)
  const float* b = (const float*)d_in[2];   // (1024,)
  float* out = (float*)d_out;               // (128, 1024) fp32

  float*          partials = (float*)((char*)d_ws + 128);        // 1024 f32
  unsigned short* Ub = (unsigned short*)((char*)d_ws + 8192);    // 1,179,648 B
  const size_t need = 8192 + (size_t)128 * KP4 * 2;              // ~1.13 MB

  if (ws_size >= need) {
    prep1_kernel<<<1168, 256, 0, stream>>>(x, w, b, partials, Ub);
    fusedgemm_kernel<<<512, 512, 0, stream>>>(w, b, partials, Ub, out);
  } else {                                 // fallback: tiny ws, atomic path
    unsigned int* wsmax = (unsigned int*)d_ws;
    hipMemsetAsync(wsmax, 0, 4, stream);
    maxabs_atomic_kernel<<<256, 256, 0, stream>>>(w, b, wsmax);
    hipMemsetAsync(out, 0, (size_t)out_size * sizeof(float), stream);
    dim3 grid(16, 16);
    memristor_atomic_kernel<<<grid, 256, 0, stream>>>(x, w, b, wsmax, out);
  }
}

// Round 11
// 22.404 us; speedup vs baseline: 9.6750x; 1.1385x over previous
//
#include <hip/hip_runtime.h>
#include <hip/hip_bf16.h>
#include <cstdint>

#define K_V_C   1.05f
#define G_DIFF  4.0e-4f   // G_MAX - G_MIN
#define KP4     4608      // k = 4*j + level (level 3 = zero pad), j padded to 1152

typedef __attribute__((ext_vector_type(8))) short short8;
typedef __attribute__((ext_vector_type(4))) float f32x4;

// I_REF rows 1..3 (row 0 is all zeros)
__device__ __constant__ float c_I1[9] = {-0.00015f,-0.00011f,-7e-05f,-3e-05f,0.f,3e-05f,7e-05f,0.00011f,0.00015f};
__device__ __constant__ float c_I2[9] = {-0.0005f,-0.00035f,-0.00022f,-9e-05f,0.f,9e-05f,0.00022f,0.00035f,0.0005f};
__device__ __constant__ float c_I3[9] = {-0.0009f,-0.0006f,-0.00037f,-0.00015f,0.f,0.00015f,0.00037f,0.0006f,0.0009f};

__device__ inline unsigned short f2bf(float f) {   // fp32 -> bf16 RNE
  unsigned int u = __float_as_uint(f);
  u += 0x7FFFu + ((u >> 16) & 1u);
  return (unsigned short)(u >> 16);
}

__device__ inline void interp3(float v, float& u1, float& u2, float& u3) {
  const float sf = v * 3.3333333333333335f + 4.0f;   // (v+1.2)/0.3
  float fs = floorf(sf);
  fs = fminf(fmaxf(fs, 0.f), 7.f);
  const int   s  = (int)fs;
  const float fr = fminf(fmaxf(sf - fs, 0.f), 1.f);
  u1 = fmaf(fr, c_I1[s+1] - c_I1[s], c_I1[s]);
  u2 = fmaf(fr, c_I2[s+1] - c_I2[s], c_I2[s]);
  u3 = fmaf(fr, c_I3[s+1] - c_I3[s], c_I3[s]);
}

// branch-free coeff3: clamped ramps, differences, sign OR'd in.
// Bit-identical to the select form: t ramps reproduce (ga-g0)*invd exactly.
__device__ inline void coeff3f(float g, float& c1, float& c2, float& c3) {
  const float    ga = fabsf(g);
  const unsigned sb = __float_as_uint(g) & 0x80000000u;
  const float t1 = fminf(ga * 1e4f, 1.f);
  const float t2 = fminf(fmaxf((ga - 1e-4f) * 5e3f, 0.f), 1.f);
  const float t3 = fmaxf((ga - 3e-4f) * 5e3f, 0.f);        // ga <= 4e-4 -> t3 <= ~0.5
  c1 = __uint_as_float(__float_as_uint(t1 - t2) | sb);
  c2 = __uint_as_float(__float_as_uint(t2 - t3) | sb);
  c3 = __uint_as_float(__float_as_uint(t3) | sb);
}

__device__ inline void coeff3(float g, float& c1, float& c2, float& c3) {
  const float ga  = fabsf(g);
  const float sgn = (g > 0.f) ? 1.f : ((g < 0.f) ? -1.f : 0.f);
  const int   idx = (ga >= 3e-4f) ? 2 : ((ga >= 1e-4f) ? 1 : 0);
  const float g0   = (idx == 0) ? 0.f : ((idx == 1) ? 1e-4f : 3e-4f);
  const float invd = (idx == 0) ? 1e4f : 5e3f;
  const float t    = (ga - g0) * invd;
  const float clo = sgn * (1.f - t), chi = sgn * t;
  c1 = (idx == 0) ? chi : ((idx == 1) ? clo : 0.f);
  c2 = (idx == 1) ? chi : ((idx == 2) ? clo : 0.f);
  c3 = (idx == 2) ? chi : 0.f;
}

// ---------------------------------------------------------------------------
// Dispatch 1: blocks 0..1023  -> per-block max(|w|,|b|) partials (no atomics)
//             blocks 1024..1167 -> prep U bf16 [128][KP4], k = 4*j + level
// ---------------------------------------------------------------------------
__global__ __launch_bounds__(256) void prep1_kernel(
    const float* __restrict__ x, const float* __restrict__ w,
    const float* __restrict__ bias, float* __restrict__ partials,
    unsigned short* __restrict__ Ub) {
  const int t = threadIdx.x, bid = blockIdx.x;
  if (bid < 1024) {                       // ---- maxabs partial ----
    const int i = bid * 256 + t;          // one float4 of w per thread
    const float4 v = ((const float4*)w)[i];
    float m = fmaxf(fmaxf(fabsf(v.x), fabsf(v.y)), fmaxf(fabsf(v.z), fabsf(v.w)));
    if (i < 256) {
      const float4 bv = ((const float4*)bias)[i];
      m = fmaxf(m, fmaxf(fmaxf(fabsf(bv.x), fabsf(bv.y)),
                         fmaxf(fabsf(bv.z), fabsf(bv.w))));
    }
    #pragma unroll
    for (int o = 32; o > 0; o >>= 1) m = fmaxf(m, __shfl_down(m, o, 64));
    __shared__ float red[4];
    if ((t & 63) == 0) red[t >> 6] = m;
    __syncthreads();
    if (t == 0)
      partials[bid] = fmaxf(fmaxf(red[0], red[1]), fmaxf(red[2], red[3]));
  } else {                                // ---- prep U ----
    const int idx = (bid - 1024) * 256 + t;   // 36864 = 128 b x 288 j4-groups
    const int b = idx / 288, j4 = idx - b * 288;
    ushort4 o0 = make_ushort4(0,0,0,0), o1 = o0, o2 = o0, o3 = o0;
    if (j4 < 256) {
      const float4 xv = ((const float4*)x)[b * 256 + j4];
      float u1, u2, u3;
      interp3(K_V_C * xv.x, u1, u2, u3); o0 = make_ushort4(f2bf(u1), f2bf(u2), f2bf(u3), 0);
      interp3(K_V_C * xv.y, u1, u2, u3); o1 = make_ushort4(f2bf(u1), f2bf(u2), f2bf(u3), 0);
      interp3(K_V_C * xv.z, u1, u2, u3); o2 = make_ushort4(f2bf(u1), f2bf(u2), f2bf(u3), 0);
      interp3(K_V_C * xv.w, u1, u2, u3); o3 = make_ushort4(f2bf(u1), f2bf(u2), f2bf(u3), 0);
    } else if (j4 == 256) {               // j = 1024: ones/bias column
      float u1, u2, u3;
      interp3(K_V_C, u1, u2, u3);
      o0 = make_ushort4(f2bf(u1), f2bf(u2), f2bf(u3), 0);
    }
    ushort4* dst = (ushort4*)(Ub + (size_t)b * KP4 + j4 * 16);
    dst[0] = o0; dst[1] = o1; dst[2] = o2; dst[3] = o3;
  }
}

// ---------------------------------------------------------------------------
// Dispatch 2: GEMM y = scale * U . C^T, C-fragments built from an LDS-staged
//   w-panel. 512 blocks (one 16x16 tile) x 8 waves (split-K x8, 144 j each).
//   LDS panel [1024 j][16 m] f32 (64 KB): inner read lds[j0*16+la] puts the
//   16 la-lanes on 16 distinct banks (kg aliasing = 4-way max); staging is a
//   contiguous ds_write_b128 per float4. P[8][256] aliases the panel after a
//   barrier. Branch-free 18-step loop, cvt_pk bf16 packing.
// ---------------------------------------------------------------------------
__global__ __launch_bounds__(512, 4) void fusedgemm_kernel(
    const float* __restrict__ w, const float* __restrict__ bias,
    const float* __restrict__ partials, const unsigned short* __restrict__ Ub,
    float* __restrict__ out) {
  __shared__ __align__(16) float lds[16384];   // 64 KB exactly
  const int t = threadIdx.x;
  const int wv = t >> 6, lane = t & 63, la = lane & 15, kg = lane >> 4;
  const int b0 = (blockIdx.x >> 6) * 16;
  const int n0 = (blockIdx.x & 63) * 16;
  const int m  = n0 + la;

  // ---- stage w-panel: lds[j][mm] = w[j][n0+mm]  (contiguous b128 writes) ----
  #pragma unroll
  for (int i = 0; i < 8; ++i) {
    const int idx = i * 512 + t;               // 4096 float4 of the panel
    const int row = idx >> 2, c4 = idx & 3;    // row = j
    const float4 v = *(const float4*)(w + (size_t)row * 1024 + n0 + c4 * 4);
    *(float4*)&lds[row * 16 + c4 * 4] = v;
  }

  // ---- maxw from all 1024 partials ----
  float mx = 0.f;
  #pragma unroll
  for (int i = 0; i < 4; ++i) {
    const float4 p = ((const float4*)partials)[lane + i * 64];
    mx = fmaxf(mx, fmaxf(fmaxf(p.x, p.y), fmaxf(p.z, p.w)));
  }
  #pragma unroll
  for (int o = 1; o < 64; o <<= 1) mx = fmaxf(mx, __shfl_xor(mx, o, 64));
  const float maxw = mx;
  const float kG   = G_DIFF / maxw;
  const float bv   = bias[m];
  __syncthreads();

  // ---- 18-step branch-free MFMA loop (wave = k-slice of 576 = 144 j) ----
  const unsigned short* Ap = Ub + (size_t)(b0 + la) * KP4 + wv * 576 + kg * 8;
  const int jb = wv * 144 + kg * 2;
  f32x4 acc = {0.f, 0.f, 0.f, 0.f};
  #pragma unroll 6
  for (int ks = 0; ks < 18; ++ks) {
    const short8 a = *(const short8*)(Ap + ks * 32);
    const int j0 = jb + ks * 8;                // this lane's two j's: j0, j0+1
    const float ra = lds[min(j0, 1023) * 16 + la];
    const float rb = lds[min(j0 + 1, 1023) * 16 + la];
    const float wa = (j0 < 1024) ? ra : ((j0 == 1024) ? bv : 0.f);
    const float wb = (j0 + 1 < 1024) ? rb : ((j0 + 1 == 1024) ? bv : 0.f);
    float a1, a2, a3, b1, b2, b3;
    coeff3f(kG * wa, a1, a2, a3);
    coeff3f(kG * wb, b1, b2, b3);
    union { __hip_bfloat162 h[4]; short8 s; } bf;
    bf.h[0] = __float22bfloat162_rn(make_float2(a1, a2));
    bf.h[1] = __float22bfloat162_rn(make_float2(a3, 0.f));
    bf.h[2] = __float22bfloat162_rn(make_float2(b1, b2));
    bf.h[3] = __float22bfloat162_rn(make_float2(b3, 0.f));
    acc = __builtin_amdgcn_mfma_f32_16x16x32_bf16(a, bf.s, acc, 0, 0, 0);
  }

  // ---- cross-wave K-reduce (P aliases the w-panel) + fused scale ----
  __syncthreads();                             // all waves done reading panel
  *(float4*)&lds[wv * 256 + lane * 4] = make_float4(acc[0], acc[1], acc[2], acc[3]);
  __syncthreads();
  if (t < 256) {
    float s = 0.f;
    #pragma unroll
    for (int ww = 0; ww < 8; ++ww) s += lds[ww * 256 + t];
    const int l2 = t >> 2, ai = t & 3;         // D: col = lane&15, row = kg*4+r
    const int row = b0 + ((l2 >> 4) << 2) + ai;
    const int col = n0 + (l2 & 15);
    out[(size_t)row * 1024 + col] = s * (maxw * (1.0f / (K_V_C * G_DIFF)));
  }
}

// ---------------------------------------------------------------------------
// Fallback (tiny ws): atomic-based path, needs only 4 bytes of ws.
// ---------------------------------------------------------------------------
__global__ __launch_bounds__(256) void maxabs_atomic_kernel(
    const float* __restrict__ w, const float* __restrict__ b,
    unsigned int* __restrict__ wsmax) {
  const int NW4 = 262144, NB4 = 256;
  float m = 0.f;
  for (int i = blockIdx.x * blockDim.x + threadIdx.x; i < NW4 + NB4;
       i += gridDim.x * blockDim.x) {
    float4 v = (i < NW4) ? ((const float4*)w)[i] : ((const float4*)b)[i - NW4];
    m = fmaxf(m, fmaxf(fmaxf(fabsf(v.x), fabsf(v.y)),
                       fmaxf(fabsf(v.z), fabsf(v.w))));
  }
  #pragma unroll
  for (int o = 32; o > 0; o >>= 1) m = fmaxf(m, __shfl_down(m, o, 64));
  __shared__ float red[4];
  if ((threadIdx.x & 63) == 0) red[threadIdx.x >> 6] = m;
  __syncthreads();
  if (threadIdx.x == 0)
    atomicMax(wsmax, __float_as_uint(fmaxf(fmaxf(red[0], red[1]),
                                           fmaxf(red[2], red[3]))));
}

__global__ __launch_bounds__(256) void memristor_atomic_kernel(
    const float* __restrict__ x, const float* __restrict__ w,
    const float* __restrict__ bias, const unsigned int* __restrict__ wsmax,
    float* __restrict__ out) {
  __shared__ float4 U[2048];
  const int tid = threadIdx.x;
  const float maxw  = __uint_as_float(*wsmax);
  const float kG    = G_DIFF / maxw;
  const float scale = maxw * (1.0f / (K_V_C * G_DIFF));
  const int mq = tid & 15, bg = tid >> 4;
  const int m0 = blockIdx.x * 64 + mq * 4;
  const int swz = bg & 7;
  float acc[4][8];
  #pragma unroll
  for (int a = 0; a < 4; ++a)
    #pragma unroll
    for (int c = 0; c < 8; ++c) acc[a][c] = 0.f;
  for (int sc = blockIdx.y; sc < 65; sc += 16) {
    const int j0 = sc * 16;
    const int nj = min(16, 1025 - j0);
    __syncthreads();
    #pragma unroll
    for (int k = 0; k < 8; ++k) {
      const int e = k * 256 + tid;
      const int jl = e & 15, b = e >> 4;
      const int jg = j0 + jl;
      if (jg <= 1024) {
        const float v = (jg < 1024) ? K_V_C * x[b * 1024 + jg] : K_V_C;
        float u1, u2, u3;
        interp3(v, u1, u2, u3);
        U[b * 16 + (jl ^ ((b >> 3) & 7))] = make_float4(0.f, u1, u2, u3);
      }
    }
    __syncthreads();
    for (int jl = 0; jl < nj; ++jl) {
      const int jg = j0 + jl;
      const float4 wv = (jg < 1024) ? *(const float4*)(w + jg * 1024 + m0)
                                    : *(const float4*)(bias + m0);
      const float warr[4] = {wv.x, wv.y, wv.z, wv.w};
      float c1[4], c2[4], c3[4];
      #pragma unroll
      for (int mi = 0; mi < 4; ++mi) coeff3(kG * warr[mi], c1[mi], c2[mi], c3[mi]);
      const int base = bg * 128 + (jl ^ swz);
      #pragma unroll
      for (int bb = 0; bb < 8; ++bb) {
        const float4 u = U[base + bb * 16];
        #pragma unroll
        for (int mi = 0; mi < 4; ++mi)
          acc[mi][bb] = fmaf(c1[mi], u.y, fmaf(c2[mi], u.z, fmaf(c3[mi], u.w, acc[mi][bb])));
      }
    }
  }
  #pragma unroll
  for (int bb = 0; bb < 8; ++bb) {
    const int b = bg * 8 + bb;
    #pragma unroll
    for (int mi = 0; mi < 4; ++mi)
      atomicAdd(&out[b * 1024 + m0 + mi], acc[mi][bb] * scale);
  }
}

// ---------------------------------------------------------------------------
extern "C" void kernel_launch(void* const* d_in, const int* in_sizes, int n_in,
                              void* d_out, int out_size, void* d_ws, size_t ws_size,
                              hipStream_t stream) {
  const float* x = (const float*)d_in[0];   // (128, 1024)
  const float* w = (const float*)d_in[1];   // (1024, 1024)
  const float* b = (const float*)d_in[2];   // (1024,)
  float* out = (float*)d_out;               // (128, 1024) fp32

  float*          partials = (float*)((char*)d_ws + 128);        // 1024 f32
  unsigned short* Ub = (unsigned short*)((char*)d_ws + 8192);    // 1,179,648 B
  const size_t need = 8192 + (size_t)128 * KP4 * 2;              // ~1.13 MB

  if (ws_size >= need) {
    prep1_kernel<<<1168, 256, 0, stream>>>(x, w, b, partials, Ub);
    fusedgemm_kernel<<<512, 512, 0, stream>>>(w, b, partials, Ub, out);
  } else {                                 // fallback: tiny ws, atomic path
    unsigned int* wsmax = (unsigned int*)d_ws;
    hipMemsetAsync(wsmax, 0, 4, stream);
    maxabs_atomic_kernel<<<256, 256, 0, stream>>>(w, b, wsmax);
    hipMemsetAsync(out, 0, (size_t)out_size * sizeof(float), stream);
    dim3 grid(16, 16);
    memristor_atomic_kernel<<<grid, 256, 0, stream>>>(x, w, b, wsmax, out);
  }
}